// Round 13
// baseline (11.052 us; speedup 1.0000x reference)
//
#include <hip/hip_runtime.h>

// out[b,n,d] = (x@Wq+bq)[b,n,d] * kv[b,d],  kv[b,d] = sum_m ((x@Wk+bk)*(x@Wv+bv))[b,m,d]
// B=4, N=1024, D=128, fp32 in/out.
//
// R13 = R11 (fused, relaxed-atomic group barrier, 10.3us) with the x-tile
// LDS staging DELETED: each lane's A-frag is 8 contiguous floats of one x
// row -> loaded directly global->reg (2 float4, issued before W staging)
// and RNE-split in registers (~50 VALU). Removes 32KB LDS, the x
// convert+store pass, and its LDS round trip; pre-MFMA sync covers W only.
// k-alignment unchanged: A uses logical slice s directly; B's swizzled read
// also resolves logical slice s (same pairing as R11 -> same numerics).
//  - LDS 48.6KB (wt only): capacity 2 blocks/CU -> all 256 blocks resident
//    regardless of placement; barrier deadlock-safe.
//  - everything else proven-identical to R11: MFMA bf16x3 RNE split
//    (v_cvt_pk_bf16_f32; terms Ah*Bh+Al*Bh+Ah*Bl), W swizzled 16B slices,
//    C/D map col=lane&15 row=(lane>>4)*4+reg, kv-first + early flag +
//    q-MFMAs overlapping the wait, relaxed agent atomics, magic-pair flag,
//    drain-sync before flag, grid 256 = #CUs.

#define NN 1024
#define DD 128
#define MAGICPAIR 0x5EEDBEEFA5F00D1Eull

typedef __attribute__((ext_vector_type(8))) short short8;
typedef __attribute__((ext_vector_type(4))) float f32x4;

union Frag { short8 s; unsigned int u[4]; };

static __device__ __forceinline__ unsigned int cvtpk(float a, float b) {
    unsigned int r;
    asm("v_cvt_pk_bf16_f32 %0, %1, %2" : "=v"(r) : "v"(a), "v"(b));
    return r;   // low16 = bf16(a), high16 = bf16(b)
}

static __device__ __forceinline__ void split2(float a, float b,
                                              unsigned int& hp, unsigned int& lp) {
    hp = cvtpk(a, b);
    const float ha = __uint_as_float(hp << 16);
    const float hb = __uint_as_float(hp & 0xFFFF0000u);
    lp = cvtpk(a - ha, b - hb);
}

__global__ __launch_bounds__(512, 2) void fused_kernel(
    const float* __restrict__ x,
    const float* __restrict__ Wq, const float* __restrict__ bq,
    const float* __restrict__ Wk, const float* __restrict__ bk,
    const float* __restrict__ Wv, const float* __restrict__ bv,
    float* __restrict__ out, float* __restrict__ ws)
{
    __shared__ __align__(16) unsigned short wt[3][2][32][DD];  // 48 KB
    __shared__ float red[4][32];                               // 512 B
    __shared__ float kvs[32];                                  // 128 B

    const int bid = blockIdx.x;          // 256 = cgi(4) x rt(64)
    const int rt  = bid & 63;            // rows rt*64 .. rt*64+63
    const int cgi = bid >> 6;            // cols cgi*32 .. cgi*32+31
    const int tid = threadIdx.x;
    const int cbase = cgi << 5;
    const int b = rt >> 4;               // batch of this row tile

    unsigned long long* flags64 = reinterpret_cast<unsigned long long*>(ws); // [256]
    float* partials = ws + 512;                                              // [64][128]

    const int lane  = tid & 63;
    const int w8    = tid >> 6;
    const int wr    = w8 >> 1;            // row subtile 0..3
    const int wc    = w8 & 1;             // col subtile 0..1
    const int lr    = lane & 15;
    const int kslot = lane >> 4;
    const int arow  = (wr << 4) + lr;     // 0..63
    const int bcol  = (wc << 4) + lr;     // 0..31

    // ---- issue this lane's x A-frag loads FIRST (8 float4s in flight) ----
    const float* xrow = x + ((size_t)rt * 64 + arow) * DD;
    float4 xra[4], xrb[4];
#pragma unroll
    for (int ks = 0; ks < 4; ++ks) {
        const float* p = xrow + ((((ks << 2) + kslot)) << 3);  // slice s * 8
        xra[ks] = *reinterpret_cast<const float4*>(p);
        xrb[ks] = *reinterpret_cast<const float4*>(p + 4);
    }

    // ---- stage W slab: thread owns (col, k-octet); 1536 units / 512 thr ----
    {
        const int col = tid & 31;
        const int ko  = (tid >> 5) & 15;             // k = 8*ko .. 8*ko+7
        const int swz = (ko ^ (col & 7)) << 4;
#pragma unroll
        for (int m = 0; m < 3; ++m) {
            const float* wp = m == 0 ? Wq : (m == 1 ? Wk : Wv);
            const float* src = wp + (size_t)(ko << 3) * DD + cbase + col;
            float e[8];
#pragma unroll
            for (int i = 0; i < 8; ++i) e[i] = src[(size_t)i * DD];
            unsigned int hp[4], lp[4];
#pragma unroll
            for (int j = 0; j < 4; ++j) split2(e[2*j], e[2*j+1], hp[j], lp[j]);
            *reinterpret_cast<int4*>((char*)&wt[m][0][col][0] + swz) =
                *reinterpret_cast<int4*>(hp);
            *reinterpret_cast<int4*>((char*)&wt[m][1][col][0] + swz) =
                *reinterpret_cast<int4*>(lp);
        }
    }

    // ---- convert A-frags in registers (overlaps W LDS writes) ----
    Frag ah[4], al[4];
#pragma unroll
    for (int ks = 0; ks < 4; ++ks) {
        split2(xra[ks].x, xra[ks].y, ah[ks].u[0], al[ks].u[0]);
        split2(xra[ks].z, xra[ks].w, ah[ks].u[1], al[ks].u[1]);
        split2(xrb[ks].x, xrb[ks].y, ah[ks].u[2], al[ks].u[2]);
        split2(xrb[ks].z, xrb[ks].w, ah[ks].u[3], al[ks].u[3]);
    }
    __syncthreads();   // W slab ready

    const char* wb   = (const char*)&wt[0][0][bcol][0];
    const int   bswz = bcol & 7;
    const int   MATS = 2 * 32 * DD * 2;   // bytes per mat
    const int   HS   = 32 * DD * 2;       // bytes per hi/lo plane

    f32x4 qa = {0.f, 0.f, 0.f, 0.f};
    f32x4 ka = {0.f, 0.f, 0.f, 0.f};
    f32x4 va = {0.f, 0.f, 0.f, 0.f};

    // ---- pass 1: k,v MFMAs (flag path carries no q work) ----
#pragma unroll
    for (int ks = 0; ks < 4; ++ks) {
        const int s   = (ks << 2) + kslot;
        const int bof = (s ^ bswz) << 4;
        Frag kh, kl, vh, vl;
        kh.s = *reinterpret_cast<const short8*>(wb + MATS + bof);
        kl.s = *reinterpret_cast<const short8*>(wb + MATS + HS + bof);
        vh.s = *reinterpret_cast<const short8*>(wb + 2 * MATS + bof);
        vl.s = *reinterpret_cast<const short8*>(wb + 2 * MATS + HS + bof);

        ka = __builtin_amdgcn_mfma_f32_16x16x32_bf16(ah[ks].s, kh.s, ka, 0, 0, 0);
        ka = __builtin_amdgcn_mfma_f32_16x16x32_bf16(al[ks].s, kh.s, ka, 0, 0, 0);
        ka = __builtin_amdgcn_mfma_f32_16x16x32_bf16(ah[ks].s, kl.s, ka, 0, 0, 0);

        va = __builtin_amdgcn_mfma_f32_16x16x32_bf16(ah[ks].s, vh.s, va, 0, 0, 0);
        va = __builtin_amdgcn_mfma_f32_16x16x32_bf16(al[ks].s, vh.s, va, 0, 0, 0);
        va = __builtin_amdgcn_mfma_f32_16x16x32_bf16(ah[ks].s, vl.s, va, 0, 0, 0);
    }

    // ---- kv partial; pre-reduce the 4 row-subtile waves in LDS ----
    const int colg = cbase + (wc << 4) + lr;
    const float bqc = bq[colg], bkc = bk[colg], bvc = bv[colg];

    float p = 0.f;
#pragma unroll
    for (int i = 0; i < 4; ++i)
        p += (ka[i] + bkc) * (va[i] + bvc);
    p += __shfl_xor(p, 16);
    p += __shfl_xor(p, 32);
    if (lane < 16) red[wr][(wc << 4) + lane] = p;
    __syncthreads();

    if (tid < 32) {
        const float s = red[0][tid] + red[1][tid] + red[2][tid] + red[3][tid];
        __hip_atomic_store(&partials[(size_t)rt * DD + cbase + tid], s,
                           __ATOMIC_RELAXED, __HIP_MEMORY_SCOPE_AGENT);
    }
    __syncthreads();   // vmcnt(0) drained -> partial stores complete

    // ---- arrive EARLY: one 8-byte magic (ordered by the drain above) ----
    if (tid == 0)
        __hip_atomic_store(&flags64[bid], (unsigned long long)MAGICPAIR,
                           __ATOMIC_RELAXED, __HIP_MEMORY_SCOPE_AGENT);

    // ---- pass 2: q MFMAs (overlap other blocks' kv phase / our wait) ----
#pragma unroll
    for (int ks = 0; ks < 4; ++ks) {
        const int s   = (ks << 2) + kslot;
        const int bof = (s ^ bswz) << 4;
        Frag qh, ql;
        qh.s = *reinterpret_cast<const short8*>(wb + bof);
        ql.s = *reinterpret_cast<const short8*>(wb + HS + bof);
        qa = __builtin_amdgcn_mfma_f32_16x16x32_bf16(ah[ks].s, qh.s, qa, 0, 0, 0);
        qa = __builtin_amdgcn_mfma_f32_16x16x32_bf16(al[ks].s, qh.s, qa, 0, 0, 0);
        qa = __builtin_amdgcn_mfma_f32_16x16x32_bf16(ah[ks].s, ql.s, qa, 0, 0, 0);
    }

    // ---- wait for the 16 blocks of this (b, cgi) group ----
    if (tid < 16) {
        const int wbid = (cgi << 6) + (b << 4) + tid;
        while (__hip_atomic_load(&flags64[wbid], __ATOMIC_RELAXED,
                                 __HIP_MEMORY_SCOPE_AGENT)
               != (unsigned long long)MAGICPAIR)
            __builtin_amdgcn_s_sleep(1);
    }
    __syncthreads();   // all waves past q-pass; wt now dead -> reuse as scratch

    // ---- kv = fixed-order sum of this batch's 16 row-tile partials ----
    {
        float* scratch = reinterpret_cast<float*>(&wt[0][0][0][0]);
        const int col = tid & 31, rr = tid >> 5;               // rr 0..15
        const float pv = __hip_atomic_load(
            &partials[(size_t)((b << 4) + rr) * DD + cbase + col],
            __ATOMIC_RELAXED, __HIP_MEMORY_SCOPE_AGENT);
        scratch[rr * 32 + col] = pv;
        __syncthreads();
        if (tid < 32) {
            float s = 0.f;
#pragma unroll
            for (int j = 0; j < 16; ++j) s += scratch[j * 32 + tid];
            kvs[tid] = s;
        }
        __syncthreads();
    }

    const float kvc = kvs[(wc << 4) + lr];
    const size_t rbase = ((size_t)rt * 64 + (wr << 4) + (kslot << 2)) * DD + colg;
#pragma unroll
    for (int i = 0; i < 4; ++i)
        out[rbase + (size_t)i * DD] = (qa[i] + bqc) * kvc;
}

extern "C" void kernel_launch(void* const* d_in, const int* in_sizes, int n_in,
                              void* d_out, int out_size, void* d_ws, size_t ws_size,
                              hipStream_t stream) {
    const float* x  = (const float*)d_in[0];
    const float* Wq = (const float*)d_in[1];
    const float* bq = (const float*)d_in[2];
    const float* Wk = (const float*)d_in[3];
    const float* bk = (const float*)d_in[4];
    const float* Wv = (const float*)d_in[5];
    const float* bv = (const float*)d_in[6];
    float* out      = (float*)d_out;
    float* ws       = (float*)d_ws;   // flags 2KB + partials 32KB

    fused_kernel<<<dim3(256), dim3(512), 0, stream>>>(
        x, Wq, bq, Wk, bk, Wv, bv, out, ws);
}

// Round 14
// 10.277 us; speedup vs baseline: 1.0754x; 1.0754x over previous
//
#include <hip/hip_runtime.h>

// out[b,n,d] = (x@Wq+bq)[b,n,d] * kv[b,d],  kv[b,d] = sum_m ((x@Wk+bk)*(x@Wv+bv))[b,m,d]
// B=4, N=1024, D=128, fp32 in/out.
//
// R14 = R11 restored verbatim (best measured: 10.29us). R12 (16 waves,
// role-split: 10.61) and R13 (no x-LDS staging: 11.05) both regressed ->
// the ~10.3us level is this structure's floor: ~3-4us of measured kernel
// work + launch/dispatch-ramp/flag-propagation overhead. Structure:
//  - fused single-pass: MFMA bf16x3 (RNE hi/lo split via v_cvt_pk_bf16_f32,
//    terms Ah*Bh+Al*Bh+Ah*Bl), k,v MFMAs first -> kv partial -> early flag
//    store -> q MFMAs (A-frags in regs) overlap the group wait -> scale+write.
//  - x tile + W slab staged in LDS (80.6KB, 1 block/CU, grid 256 = #CUs);
//    swizzled 16B slices, shared A/B k-permutation; C/D map col=lane&15,
//    row=(lane>>4)*4+reg (HW-verified).
//  - group barrier: 16 blocks sharing (b,cgi); relaxed agent-scope atomics
//    (no acquire-invalidate storm - R9's 86us lesson), single 8-byte
//    magic-pair flag, s_sleep(1) poll by 16 lanes; drain-sync orders
//    partials before flag. Poison-safe + replay-safe.

#define NN 1024
#define DD 128
#define MAGICPAIR 0x5EEDBEEFA5F00D1Eull   // two distinct-byte magic words

typedef __attribute__((ext_vector_type(8))) short short8;
typedef __attribute__((ext_vector_type(4))) float f32x4;

union Frag { short8 s; unsigned int u[4]; };

static __device__ __forceinline__ unsigned int cvtpk(float a, float b) {
    unsigned int r;
    asm("v_cvt_pk_bf16_f32 %0, %1, %2" : "=v"(r) : "v"(a), "v"(b));
    return r;   // low16 = bf16(a), high16 = bf16(b)
}

static __device__ __forceinline__ void split2(float a, float b,
                                              unsigned int& hp, unsigned int& lp) {
    hp = cvtpk(a, b);
    const float ha = __uint_as_float(hp << 16);
    const float hb = __uint_as_float(hp & 0xFFFF0000u);
    lp = cvtpk(a - ha, b - hb);
}

__global__ __launch_bounds__(512, 2) void fused_kernel(
    const float* __restrict__ x,
    const float* __restrict__ Wq, const float* __restrict__ bq,
    const float* __restrict__ Wk, const float* __restrict__ bk,
    const float* __restrict__ Wv, const float* __restrict__ bv,
    float* __restrict__ out, float* __restrict__ ws)
{
    __shared__ __align__(16) unsigned short xh[64][DD];        // 16 KB
    __shared__ __align__(16) unsigned short xl[64][DD];        // 16 KB
    __shared__ __align__(16) unsigned short wt[3][2][32][DD];  // 48 KB
    __shared__ float red[4][32];                               // 512 B
    __shared__ float kvs[32];                                  // 128 B

    const int bid = blockIdx.x;          // 256 = cgi(4) x rt(64)
    const int rt  = bid & 63;            // rows rt*64 .. rt*64+63
    const int cgi = bid >> 6;            // cols cgi*32 .. cgi*32+31
    const int tid = threadIdx.x;
    const int cbase = cgi << 5;
    const int b = rt >> 4;               // batch of this row tile

    unsigned long long* flags64 = reinterpret_cast<unsigned long long*>(ws); // [256]
    float* partials = ws + 512;                                              // [64][128]

    // ---- prefetch x tile to regs (issued before W loads/converts) ----
    float4 xr[4];
    {
        const float4* src = reinterpret_cast<const float4*>(x + (size_t)rt * 64 * DD);
#pragma unroll
        for (int j = 0; j < 4; ++j) xr[j] = src[tid + j * 512];
    }

    // ---- stage W slab: thread owns (col, k-octet) ----
    {
        const int col = tid & 31;
        const int ko  = (tid >> 5) & 15;             // k = 8*ko .. 8*ko+7
        const int swz = (ko ^ (col & 7)) << 4;
#pragma unroll
        for (int m = 0; m < 3; ++m) {
            const float* wp = m == 0 ? Wq : (m == 1 ? Wk : Wv);
            const float* src = wp + (size_t)(ko << 3) * DD + cbase + col;
            float e[8];
#pragma unroll
            for (int i = 0; i < 8; ++i) e[i] = src[(size_t)i * DD];
            unsigned int hp[4], lp[4];
#pragma unroll
            for (int j = 0; j < 4; ++j) split2(e[2*j], e[2*j+1], hp[j], lp[j]);
            *reinterpret_cast<int4*>((char*)&wt[m][0][col][0] + swz) =
                *reinterpret_cast<int4*>(hp);
            *reinterpret_cast<int4*>((char*)&wt[m][1][col][0] + swz) =
                *reinterpret_cast<int4*>(lp);
        }
    }

    // ---- convert prefetched x tile -> hi/lo planes ----
    {
#pragma unroll
        for (int j = 0; j < 4; ++j) {
            const int idx = tid + j * 512;           // 0..2047 float4s
            const float4 v = xr[j];
            const int row = idx >> 5, c4 = idx & 31;
            const int s = c4 >> 1, half = c4 & 1;
            const int off = ((s ^ (row & 7)) << 4) + (half << 3);
            unsigned int h0, l0, h1, l1;
            split2(v.x, v.y, h0, l0);
            split2(v.z, v.w, h1, l1);
            const unsigned long long hp =
                (unsigned long long)h0 | ((unsigned long long)h1 << 32);
            const unsigned long long lp =
                (unsigned long long)l0 | ((unsigned long long)l1 << 32);
            *reinterpret_cast<unsigned long long*>((char*)&xh[row][0] + off) = hp;
            *reinterpret_cast<unsigned long long*>((char*)&xl[row][0] + off) = lp;
        }
    }
    __syncthreads();

    // ---- MFMA setup: wave (wr 0..3, wc 0..1) -> one 16x16 tile ----
    const int lane  = tid & 63;
    const int w8    = tid >> 6;
    const int wr    = w8 >> 1;
    const int wc    = w8 & 1;
    const int lr    = lane & 15;
    const int kslot = lane >> 4;
    const int arow  = (wr << 4) + lr;     // 0..63
    const int bcol  = (wc << 4) + lr;     // 0..31

    f32x4 qa = {0.f, 0.f, 0.f, 0.f};
    f32x4 ka = {0.f, 0.f, 0.f, 0.f};
    f32x4 va = {0.f, 0.f, 0.f, 0.f};

    const char* xhp = (const char*)&xh[arow][0];
    const char* xlp = (const char*)&xl[arow][0];
    const int   aswz = arow & 7;
    const char* wb   = (const char*)&wt[0][0][bcol][0];
    const int   bswz = bcol & 7;
    const int   MATS = 2 * 32 * DD * 2;   // bytes per mat
    const int   HS   = 32 * DD * 2;       // bytes per hi/lo plane

    Frag ah[4], al[4];                    // A-frags saved for the q pass

    // ---- pass 1: k,v MFMAs ----
#pragma unroll
    for (int ks = 0; ks < 4; ++ks) {
        const int s   = (ks << 2) + kslot;            // 16B slice 0..15
        const int aof = (s ^ aswz) << 4;
        const int bof = (s ^ bswz) << 4;
        Frag kh, kl, vh, vl;
        ah[ks].s = *reinterpret_cast<const short8*>(xhp + aof);
        al[ks].s = *reinterpret_cast<const short8*>(xlp + aof);
        kh.s = *reinterpret_cast<const short8*>(wb + MATS + bof);
        kl.s = *reinterpret_cast<const short8*>(wb + MATS + HS + bof);
        vh.s = *reinterpret_cast<const short8*>(wb + 2 * MATS + bof);
        vl.s = *reinterpret_cast<const short8*>(wb + 2 * MATS + HS + bof);

        ka = __builtin_amdgcn_mfma_f32_16x16x32_bf16(ah[ks].s, kh.s, ka, 0, 0, 0);
        ka = __builtin_amdgcn_mfma_f32_16x16x32_bf16(al[ks].s, kh.s, ka, 0, 0, 0);
        ka = __builtin_amdgcn_mfma_f32_16x16x32_bf16(ah[ks].s, kl.s, ka, 0, 0, 0);

        va = __builtin_amdgcn_mfma_f32_16x16x32_bf16(ah[ks].s, vh.s, va, 0, 0, 0);
        va = __builtin_amdgcn_mfma_f32_16x16x32_bf16(al[ks].s, vh.s, va, 0, 0, 0);
        va = __builtin_amdgcn_mfma_f32_16x16x32_bf16(ah[ks].s, vl.s, va, 0, 0, 0);
    }

    // ---- kv partial; pre-reduce 4 row-subtile waves in LDS ----
    const int colg = cbase + (wc << 4) + lr;
    const float bqc = bq[colg], bkc = bk[colg], bvc = bv[colg];

    float p = 0.f;
#pragma unroll
    for (int i = 0; i < 4; ++i)
        p += (ka[i] + bkc) * (va[i] + bvc);
    p += __shfl_xor(p, 16);
    p += __shfl_xor(p, 32);
    if (lane < 16) red[wr][(wc << 4) + lane] = p;
    __syncthreads();

    if (tid < 32) {
        const float s = red[0][tid] + red[1][tid] + red[2][tid] + red[3][tid];
        __hip_atomic_store(&partials[(size_t)rt * DD + cbase + tid], s,
                           __ATOMIC_RELAXED, __HIP_MEMORY_SCOPE_AGENT);
    }
    __syncthreads();   // vmcnt(0) drained -> partial stores complete

    // ---- arrive EARLY: one 8-byte magic (ordered by the drain above) ----
    if (tid == 0)
        __hip_atomic_store(&flags64[bid], (unsigned long long)MAGICPAIR,
                           __ATOMIC_RELAXED, __HIP_MEMORY_SCOPE_AGENT);

    // ---- pass 2: q MFMAs (overlaps other blocks' kv phase / our wait) ----
#pragma unroll
    for (int ks = 0; ks < 4; ++ks) {
        const int s   = (ks << 2) + kslot;
        const int bof = (s ^ bswz) << 4;
        Frag qh, ql;
        qh.s = *reinterpret_cast<const short8*>(wb + bof);
        ql.s = *reinterpret_cast<const short8*>(wb + HS + bof);
        qa = __builtin_amdgcn_mfma_f32_16x16x32_bf16(ah[ks].s, qh.s, qa, 0, 0, 0);
        qa = __builtin_amdgcn_mfma_f32_16x16x32_bf16(al[ks].s, qh.s, qa, 0, 0, 0);
        qa = __builtin_amdgcn_mfma_f32_16x16x32_bf16(ah[ks].s, ql.s, qa, 0, 0, 0);
    }

    // ---- wait for the 16 blocks of this (b, cgi) group ----
    if (tid < 16) {
        const int wbid = (cgi << 6) + (b << 4) + tid;   // watched block
        while (__hip_atomic_load(&flags64[wbid], __ATOMIC_RELAXED,
                                 __HIP_MEMORY_SCOPE_AGENT)
               != (unsigned long long)MAGICPAIR)
            __builtin_amdgcn_s_sleep(1);
    }
    __syncthreads();

    // ---- kv = fixed-order sum of this batch's 16 row-tile partials ----
    {
        float* scratch = reinterpret_cast<float*>(&xh[0][0]);  // LDS reuse
        const int col = tid & 31, rr = tid >> 5;               // rr 0..15
        const float pv = __hip_atomic_load(
            &partials[(size_t)((b << 4) + rr) * DD + cbase + col],
            __ATOMIC_RELAXED, __HIP_MEMORY_SCOPE_AGENT);
        scratch[rr * 32 + col] = pv;
        __syncthreads();
        if (tid < 32) {
            float s = 0.f;
#pragma unroll
            for (int j = 0; j < 16; ++j) s += scratch[j * 32 + tid];
            kvs[tid] = s;
        }
        __syncthreads();
    }

    const float kvc = kvs[(wc << 4) + lr];
    const size_t rbase = ((size_t)rt * 64 + (wr << 4) + (kslot << 2)) * DD + colg;
#pragma unroll
    for (int i = 0; i < 4; ++i)
        out[rbase + (size_t)i * DD] = (qa[i] + bqc) * kvc;
}

extern "C" void kernel_launch(void* const* d_in, const int* in_sizes, int n_in,
                              void* d_out, int out_size, void* d_ws, size_t ws_size,
                              hipStream_t stream) {
    const float* x  = (const float*)d_in[0];
    const float* Wq = (const float*)d_in[1];
    const float* bq = (const float*)d_in[2];
    const float* Wk = (const float*)d_in[3];
    const float* bk = (const float*)d_in[4];
    const float* Wv = (const float*)d_in[5];
    const float* bv = (const float*)d_in[6];
    float* out      = (float*)d_out;
    float* ws       = (float*)d_ws;   // flags 2KB + partials 32KB

    fused_kernel<<<dim3(256), dim3(512), 0, stream>>>(
        x, Wq, bq, Wk, bk, Wv, bv, out, ws);
}